// Round 6
// baseline (80.224 us; speedup 1.0000x reference)
//
#include <hip/hip_runtime.h>

// ZBL repulsion energy: out[b] = sum_{n,k} KEHALF * f(a*d) * Zi*Zj*mask / d
// B=16, N=8192, K=128 in the bench (shapes derived from in_sizes).
//
// Round-6 design (round-5 post-mortem: LUT cut VALU 31->16% but time flat at
// ~78us -> pure latency bound; 24.6KB LDS capped occupancy at 6 blocks/CU and
// prefetch distance 1 pass << 900cy HBM latency):
//  - exp2 mixture back in VALU (headroom); LDS = 16KB atom tab only
//    -> 8 blocks/CU = 32 waves/CU (HW max occupancy).
//  - depth-2 register software pipeline: passes g+2,g+3 issued before
//    computing g,g+1; __launch_bounds__(256,8) pins VGPR <= 64.
//  - PASSES=4 (span 4096 edges/block) -> grid (256,16) = 4096 blocks,
//    2 residency rounds; tab re-staged per block (16KB, trivial).

#define KEHALF_F 7.199822675975274f
#define LOG2E_F  1.4426950408889634f
#define EPP      1024     // edges per pass per block (256 thr x 4)
#define PASSES   4        // passes per block (span = 4096 edges)

__device__ __forceinline__ float softplus_f(float x) {
    return (x > 20.f) ? x : log1pf(__expf(x));
}

// ---------------- precompute: scalars + packed u16 per-atom table ----------------
__global__ void zbl_pre(const int* __restrict__ zn,
                        const float* __restrict__ adiv,
                        const float* __restrict__ apow,
                        const float* __restrict__ c1, const float* __restrict__ c2,
                        const float* __restrict__ c3, const float* __restrict__ c4,
                        const float* __restrict__ a1, const float* __restrict__ a2,
                        const float* __restrict__ a3, const float* __restrict__ a4,
                        unsigned short* __restrict__ packed, float* __restrict__ scal,
                        int total_atoms)
{
    int i = blockIdx.x * blockDim.x + threadIdx.x;
    const float spa = softplus_f(apow[0]);
    const float sad = softplus_f(adiv[0]);
    const float qb  = sad;                                  // Z=1 -> zps=sad
    const float qmax = sad * __expf(spa * __logf(94.f));
    const float qs  = (qmax - qb) * (1.f / 511.f);
    if (i == 0) {
        float s1 = softplus_f(c1[0]), s2 = softplus_f(c2[0]);
        float s3 = softplus_f(c3[0]), s4 = softplus_f(c4[0]);
        float inv = KEHALF_F / (s1 + s2 + s3 + s4);         // fold KEHALF
        scal[0] = sad;
        scal[1] = s1 * inv;
        scal[2] = s2 * inv;
        scal[3] = s3 * inv;
        scal[4] = s4 * inv;
        scal[5] = -softplus_f(a1[0]) * LOG2E_F;             // fold log2(e): exp2
        scal[6] = -softplus_f(a2[0]) * LOG2E_F;
        scal[7] = -softplus_f(a3[0]) * LOG2E_F;
        scal[8] = -softplus_f(a4[0]) * LOG2E_F;
        scal[9]  = qb;
        scal[10] = qs;
    }
    if (i < total_atoms) {
        unsigned int Z = (unsigned int)zn[i];
        float Zf = (float)Z;
        float zps = sad * __expf(spa * __logf(Zf));         // sp(adiv) * Z^sp(apow)
        float qf = (zps - qb) / qs;
        int q = (int)(qf + 0.5f);
        if (q < 0) q = 0;
        if (q > 511) q = 511;
        packed[i] = (unsigned short)(((unsigned)q << 7) | (Z & 0x7Fu));
    }
}

// ---------------- main: depth-2 reg pipeline + LDS atom tab ----------------
extern __shared__ char smem[];   // N u16 tab

__global__ __launch_bounds__(256, 8) void zbl_main6(
        const int*            __restrict__ neighbors,
        const float*          __restrict__ mask,
        const float*          __restrict__ dist,
        const unsigned short* __restrict__ packed,
        const float*          __restrict__ scal,
        float*                __restrict__ out,
        int N, int kshift, int epb)
{
    unsigned short* tab = (unsigned short*)smem;

    const int tid = threadIdx.x;
    const int b   = blockIdx.y;
    const int r0  = blockIdx.x * (PASSES << 10) + tid * 4;   // within-batch edge idx
    const size_t base = (size_t)b * epb + r0;
    const int*   nb = neighbors + base;
    const float* mk = mask      + base;
    const float* ds = dist      + base;

    // prologue: issue pass 0 and 1 streaming loads (overlap with staging)
    int4   Ai = *(const int4*)nb;
    float4 Am = *(const float4*)mk;
    float4 Ad = *(const float4*)ds;
    int4   Bi = *(const int4*)(nb + EPP);
    float4 Bm = *(const float4*)(mk + EPP);
    float4 Bd = *(const float4*)(ds + EPP);

    // stage atom table into LDS (coalesced 16B copies)
    {
        const uint4* s4 = (const uint4*)(packed + (size_t)b * N);
        uint4* t4 = (uint4*)tab;
        for (int i = tid, e = N >> 3; i < e; i += 256) t4[i] = s4[i];
    }
    const float w1 = scal[1], w2 = scal[2], w3 = scal[3], w4 = scal[4];
    const float e1 = scal[5], e2 = scal[6], e3 = scal[7], e4 = scal[8];
    const float qb = scal[9], qs = scal[10];
    __syncthreads();

    float acc = 0.f;

    auto compute = [&](int g, int4 gi, float4 gm, float4 gd) {
        const unsigned int wi = tab[(r0 + (g << 10)) >> kshift];
        const float zpi = fmaf((float)(wi >> 7), qs, qb);
        const float Zi  = (float)(wi & 0x7Fu);
        const int   idxs[4] = { gi.x, gi.y, gi.z, gi.w };
        const float mm[4]   = { gm.x, gm.y, gm.z, gm.w };
        const float dd[4]   = { gd.x, gd.y, gd.z, gd.w };
        #pragma unroll
        for (int u = 0; u < 4; ++u) {
            const unsigned int wj = tab[idxs[u]];
            const float zpj = fmaf((float)(wj >> 7), qs, qb);
            const float Zj  = (float)(wj & 0x7Fu);
            const float m = mm[u], d = dd[u];
            const float zz = Zi * Zj * m;
            const float ad = (zpi + zpj) * (m * d);
            const float f = w1 * exp2f(e1 * ad)
                          + w2 * exp2f(e2 * ad)
                          + w3 * exp2f(e3 * ad)
                          + w4 * exp2f(e4 * ad);
            const float gc = f * zz * __builtin_amdgcn_rcpf(d);
            acc += (m != 0.f) ? gc : 0.f;
        }
    };

    #pragma unroll
    for (int g = 0; g < PASSES; g += 2) {
        int4 nAi, nBi; float4 nAm, nAd, nBm, nBd;
        const bool pA = (g + 2 < PASSES);
        const bool pB = (g + 3 < PASSES);
        if (pA) {
            nAi = *(const int4*)(nb + ((g + 2) << 10));
            nAm = *(const float4*)(mk + ((g + 2) << 10));
            nAd = *(const float4*)(ds + ((g + 2) << 10));
        }
        if (pB) {
            nBi = *(const int4*)(nb + ((g + 3) << 10));
            nBm = *(const float4*)(mk + ((g + 3) << 10));
            nBd = *(const float4*)(ds + ((g + 3) << 10));
        }
        compute(g,     Ai, Am, Ad);
        compute(g + 1, Bi, Bm, Bd);
        if (pA) { Ai = nAi; Am = nAm; Ad = nAd; }
        if (pB) { Bi = nBi; Bm = nBm; Bd = nBd; }
    }

    // wave reduce, cross-wave via LDS, one atomic per block
    #pragma unroll
    for (int off = 32; off > 0; off >>= 1) acc += __shfl_down(acc, off);
    __shared__ float wsum[4];
    const int w = tid >> 6, lane = tid & 63;
    if (lane == 0) wsum[w] = acc;
    __syncthreads();
    if (tid == 0) atomicAdd(&out[b], wsum[0] + wsum[1] + wsum[2] + wsum[3]);
}

// ---------------- fallback (generic shapes, not used in bench) ----------------
__global__ void zbl_fallback(const int* __restrict__ neighbors,
                             const float* __restrict__ mask,
                             const float* __restrict__ dist,
                             const unsigned short* __restrict__ packed,
                             const float* __restrict__ scal,
                             float* __restrict__ out,
                             int N, int K, int epb, int total_edges)
{
    const int e = blockIdx.x * blockDim.x + threadIdx.x;
    if (e >= total_edges) return;
    const float w1 = scal[1], w2 = scal[2], w3 = scal[3], w4 = scal[4];
    const float e1 = scal[5], e2 = scal[6], e3 = scal[7], e4 = scal[8];
    const float qb = scal[9], qs = scal[10];
    const int b = e / epb;
    const int n = (e - b * epb) / K;
    const unsigned int wi = packed[(size_t)b * N + n];
    const unsigned int wj = packed[(size_t)b * N + neighbors[e]];
    const float zpi = fmaf((float)(wi >> 7), qs, qb);
    const float zpj = fmaf((float)(wj >> 7), qs, qb);
    const float Zi = (float)(wi & 0x7Fu), Zj = (float)(wj & 0x7Fu);
    const float m = mask[e], d = dist[e];
    const float a  = (zpi + zpj) * m;
    const float ad = a * d;
    const float f = w1 * exp2f(e1 * ad) + w2 * exp2f(e2 * ad)
                  + w3 * exp2f(e3 * ad) + w4 * exp2f(e4 * ad);
    const float corr = (m != 0.f) ? (f * Zi * Zj * m / d) : 0.f;
    if (corr != 0.f) atomicAdd(&out[b], corr);
}

extern "C" void kernel_launch(void* const* d_in, const int* in_sizes, int n_in,
                              void* d_out, int out_size, void* d_ws, size_t ws_size,
                              hipStream_t stream) {
    const int*   neighbors = (const int*)  d_in[0];
    const float* nb_mask   = (const float*)d_in[1];
    const int*   zn        = (const int*)  d_in[2];
    const float* dist      = (const float*)d_in[3];
    const float* adiv = (const float*)d_in[4];
    const float* apow = (const float*)d_in[5];
    const float* c1 = (const float*)d_in[6];
    const float* c2 = (const float*)d_in[7];
    const float* c3 = (const float*)d_in[8];
    const float* c4 = (const float*)d_in[9];
    const float* a1 = (const float*)d_in[10];
    const float* a2 = (const float*)d_in[11];
    const float* a3 = (const float*)d_in[12];
    const float* a4 = (const float*)d_in[13];

    const int total_edges = in_sizes[0];   // B*N*K
    const int total_atoms = in_sizes[2];   // B*N
    const int B = out_size;                // [B,1] fp32 output
    const int N = total_atoms / B;
    const int K = total_edges / total_atoms;
    const int epb = N * K;

    float*          scal   = (float*)d_ws;                         // 11 f32
    unsigned short* packed = (unsigned short*)((char*)d_ws + 64);  // B*N u16

    hipMemsetAsync(d_out, 0, (size_t)out_size * sizeof(float), stream);

    {
        const int threads = 256;
        const int blocks = (total_atoms + threads - 1) / threads;
        zbl_pre<<<blocks, threads, 0, stream>>>(zn, adiv, apow, c1, c2, c3, c4,
                                                a1, a2, a3, a4,
                                                packed, scal, total_atoms);
    }

    int kshift = 0;
    while ((1 << kshift) < K && kshift < 30) kshift++;
    const bool kpow2 = ((1 << kshift) == K);

    const size_t lds_bytes = (size_t)N * 2;
    const bool fast = kpow2 && (K % 4 == 0) && (N % 8 == 0) &&
                      (epb % (EPP * PASSES) == 0) &&
                      (lds_bytes <= 40960) &&
                      ((size_t)(64 + (size_t)total_atoms * 2) <= ws_size);
    if (fast) {
        const int bpb = epb / (EPP * PASSES);          // blocks per batch
        dim3 grid(bpb, B);
        zbl_main6<<<grid, 256, lds_bytes, stream>>>(
            neighbors, nb_mask, dist, packed, scal, (float*)d_out,
            N, kshift, epb);
    } else {
        const int threads = 256;
        const int blocks = (total_edges + threads - 1) / threads;
        zbl_fallback<<<blocks, threads, 0, stream>>>(
            neighbors, nb_mask, dist, packed, scal, (float*)d_out,
            N, K, epb, total_edges);
    }
}

// Round 7
// 53.909 us; speedup vs baseline: 1.4881x; 1.4881x over previous
//
#include <hip/hip_runtime.h>

// ZBL repulsion energy: out[b] = sum_{n,k} KEHALF * f(a*d) * Zi*Zj*mask / d
// B=16, N=8192, K=128 in the bench (shapes derived from in_sizes).
//
// Round-7: combine R4's counted-vmcnt async ring (global_load_lds, wave-
// private, NO barriers in loop) with full occupancy.
//  - granule 64 edges/iter/wave -> slot = 256B idx | 256B mask | 256B dist.
//  - depth-4 ring = 3KB/wave; 512-thr blocks (8 waves) share one 16KB tab:
//    LDS/block = 24576 + 16384 = 40960 B exactly -> 4 blocks/CU = 32 waves/CU.
//  - steady state: 12 loads in flight, s_waitcnt vmcnt(9); epilogue 9/6/3/0.
//  - __launch_bounds__(512,8) pins VGPR<=64 for 4 blocks/CU.

#define KEHALF_F 7.199822675975274f
#define LOG2E_F  1.4426950408889634f
#define DEPTH    4
#define GRAN     64       // edges per wave-iteration
#define WPB      8        // waves per block (512 threads)
#define SLOTB    768      // 256B idx + 256B mask + 256B dist

__device__ __forceinline__ float softplus_f(float x) {
    return (x > 20.f) ? x : log1pf(__expf(x));
}

// ---------------- precompute: scalars + packed u16 per-atom table ----------------
__global__ void zbl_pre(const int* __restrict__ zn,
                        const float* __restrict__ adiv,
                        const float* __restrict__ apow,
                        const float* __restrict__ c1, const float* __restrict__ c2,
                        const float* __restrict__ c3, const float* __restrict__ c4,
                        const float* __restrict__ a1, const float* __restrict__ a2,
                        const float* __restrict__ a3, const float* __restrict__ a4,
                        unsigned short* __restrict__ packed, float* __restrict__ scal,
                        int total_atoms)
{
    int i = blockIdx.x * blockDim.x + threadIdx.x;
    const float spa = softplus_f(apow[0]);
    const float sad = softplus_f(adiv[0]);
    const float qb  = sad;                                  // Z=1 -> zps=sad
    const float qmax = sad * __expf(spa * __logf(94.f));
    const float qs  = (qmax - qb) * (1.f / 511.f);
    if (i == 0) {
        float s1 = softplus_f(c1[0]), s2 = softplus_f(c2[0]);
        float s3 = softplus_f(c3[0]), s4 = softplus_f(c4[0]);
        float inv = KEHALF_F / (s1 + s2 + s3 + s4);         // fold KEHALF
        scal[0] = sad;
        scal[1] = s1 * inv;
        scal[2] = s2 * inv;
        scal[3] = s3 * inv;
        scal[4] = s4 * inv;
        scal[5] = -softplus_f(a1[0]) * LOG2E_F;             // fold log2(e): exp2
        scal[6] = -softplus_f(a2[0]) * LOG2E_F;
        scal[7] = -softplus_f(a3[0]) * LOG2E_F;
        scal[8] = -softplus_f(a4[0]) * LOG2E_F;
        scal[9]  = qb;
        scal[10] = qs;
    }
    if (i < total_atoms) {
        unsigned int Z = (unsigned int)zn[i];
        float Zf = (float)Z;
        float zps = sad * __expf(spa * __logf(Zf));         // sp(adiv) * Z^sp(apow)
        float qf = (zps - qb) / qs;
        int q = (int)(qf + 0.5f);
        if (q < 0) q = 0;
        if (q > 511) q = 511;
        packed[i] = (unsigned short)(((unsigned)q << 7) | (Z & 0x7Fu));
    }
}

// ---------------- main: depth-4 async ring, 32 waves/CU ----------------
extern __shared__ unsigned short tab[];   // N u16 (dynamic, after static)

#define STAGE(slotp, it) do {                                                     \
    const int off = (it) * GRAN + lane;                                           \
    __builtin_amdgcn_global_load_lds(                                             \
        (const __attribute__((address_space(1))) void*)(nb_ + off),               \
        (__attribute__((address_space(3))) void*)(slotp), 4, 0, 0);               \
    __builtin_amdgcn_global_load_lds(                                             \
        (const __attribute__((address_space(1))) void*)(mk_ + off),               \
        (__attribute__((address_space(3))) void*)((slotp) + 256), 4, 0, 0);       \
    __builtin_amdgcn_global_load_lds(                                             \
        (const __attribute__((address_space(1))) void*)(ds_ + off),               \
        (__attribute__((address_space(3))) void*)((slotp) + 512), 4, 0, 0);       \
} while (0)

#define CONSUME(sp, it) do {                                                      \
    const int   ji = *(const int*)  ((sp) + (lane << 2));                         \
    const float mm = *(const float*)((sp) + 256 + (lane << 2));                   \
    const float dd = *(const float*)((sp) + 512 + (lane << 2));                   \
    const int r = rw + ((it) << 6) + lane;                                        \
    const unsigned int wi_ = tab[r >> kshift];                                    \
    const unsigned int wj_ = tab[ji];                                             \
    const float zpi = fmaf((float)(wi_ >> 7), qs, qb);                            \
    const float Zi  = (float)(wi_ & 0x7Fu);                                       \
    const float zpj = fmaf((float)(wj_ >> 7), qs, qb);                            \
    const float Zj  = (float)(wj_ & 0x7Fu);                                       \
    const float zz = Zi * Zj * mm;                                                \
    const float ad = (zpi + zpj) * (mm * dd);                                     \
    const float f = w1 * exp2f(e1 * ad) + w2 * exp2f(e2 * ad)                     \
                  + w3 * exp2f(e3 * ad) + w4 * exp2f(e4 * ad);                    \
    const float gc = f * zz * __builtin_amdgcn_rcpf(dd);                          \
    acc += (mm != 0.f) ? gc : 0.f;                                                \
} while (0)

__global__ __launch_bounds__(512, 8) void zbl_main7(
        const int*            __restrict__ neighbors,
        const float*          __restrict__ mask,
        const float*          __restrict__ dist,
        const unsigned short* __restrict__ packed,
        const float*          __restrict__ scal,
        float*                __restrict__ out,
        int N, int kshift, int epb, int iters)
{
    __shared__ char stage[WPB][DEPTH][SLOTB];   // 24576 B static

    const int tid  = threadIdx.x;
    const int w    = tid >> 6;
    const int lane = tid & 63;
    const int b    = blockIdx.y;

    // wave's contiguous edge span within batch b
    const int rw = (blockIdx.x * WPB + w) * (iters * GRAN);
    const size_t ebase = (size_t)b * epb + (size_t)rw;
    const int*   nb_ = neighbors + ebase;
    const float* mk_ = mask      + ebase;
    const float* ds_ = dist      + ebase;

    // 1) tab global loads first (oldest in vmem queue)
    const uint4* s4 = (const uint4*)(packed + (size_t)b * N);
    const int n8 = N >> 3;                      // # of uint4 (<= 1024)
    uint4 tv0, tv1;
    const bool h0 = (tid < n8);
    const bool h1 = (tid + 512 < n8);
    if (h0) tv0 = s4[tid];
    if (h1) tv1 = s4[tid + 512];

    // 2) ring prologue: issue DEPTH iterations of async loads
    {
        char* sp0 = &stage[w][0][0];
        STAGE(sp0, 0);
        char* sp1 = &stage[w][1][0];
        STAGE(sp1, 1);
        char* sp2 = &stage[w][2][0];
        STAGE(sp2, 2);
        char* sp3 = &stage[w][3][0];
        STAGE(sp3, 3);
    }

    // 3) write tab to LDS (compiler waits only the tab loads), then barrier
    {
        uint4* t4 = (uint4*)tab;
        if (h0) t4[tid] = tv0;
        if (h1) t4[tid + 512] = tv1;
    }
    const float w1 = scal[1], w2 = scal[2], w3 = scal[3], w4 = scal[4];
    const float e1 = scal[5], e2 = scal[6], e3 = scal[7], e4 = scal[8];
    const float qb = scal[9], qs = scal[10];
    __syncthreads();

    float acc = 0.f;
    int it = 0;

    // main loop: steady-state counted wait, restage same slot, no barriers
    for (; it < iters - DEPTH; ++it) {
        asm volatile("s_waitcnt vmcnt(9)" ::: "memory");
        char* sp = &stage[w][it & (DEPTH - 1)][0];
        const int   ji = *(const int*)  (sp + (lane << 2));
        const float mm = *(const float*)(sp + 256 + (lane << 2));
        const float dd = *(const float*)(sp + 512 + (lane << 2));
        asm volatile("s_waitcnt lgkmcnt(0)" ::: "memory");   // slot consumed
        STAGE(sp, it + DEPTH);
        const int r = rw + (it << 6) + lane;
        const unsigned int wi_ = tab[r >> kshift];
        const unsigned int wj_ = tab[ji];
        const float zpi = fmaf((float)(wi_ >> 7), qs, qb);
        const float Zi  = (float)(wi_ & 0x7Fu);
        const float zpj = fmaf((float)(wj_ >> 7), qs, qb);
        const float Zj  = (float)(wj_ & 0x7Fu);
        const float zz = Zi * Zj * mm;
        const float ad = (zpi + zpj) * (mm * dd);
        const float f = w1 * exp2f(e1 * ad) + w2 * exp2f(e2 * ad)
                      + w3 * exp2f(e3 * ad) + w4 * exp2f(e4 * ad);
        const float gc = f * zz * __builtin_amdgcn_rcpf(dd);
        acc += (mm != 0.f) ? gc : 0.f;
    }

    // epilogue: 4 iterations with tightening waits (9/6/3/0), no restage
    {
        asm volatile("s_waitcnt vmcnt(9)" ::: "memory");
        char* sp = &stage[w][it & (DEPTH - 1)][0];
        CONSUME(sp, it); ++it;
    }
    {
        asm volatile("s_waitcnt vmcnt(6)" ::: "memory");
        char* sp = &stage[w][it & (DEPTH - 1)][0];
        CONSUME(sp, it); ++it;
    }
    {
        asm volatile("s_waitcnt vmcnt(3)" ::: "memory");
        char* sp = &stage[w][it & (DEPTH - 1)][0];
        CONSUME(sp, it); ++it;
    }
    {
        asm volatile("s_waitcnt vmcnt(0)" ::: "memory");
        char* sp = &stage[w][it & (DEPTH - 1)][0];
        CONSUME(sp, it); ++it;
    }

    // reduce: wave shuffle, then cross-wave via reused stage LDS, one atomic
    #pragma unroll
    for (int off = 32; off > 0; off >>= 1) acc += __shfl_down(acc, off);
    __syncthreads();                        // all waves past vmcnt(0)
    float* wred = (float*)&stage[0][0][0];  // reuse (all ring traffic done)
    if (lane == 0) wred[w] = acc;
    __syncthreads();
    if (tid == 0) {
        float t = 0.f;
        #pragma unroll
        for (int i = 0; i < WPB; ++i) t += wred[i];
        atomicAdd(&out[b], t);
    }
}

// ---------------- fallback (generic shapes, not used in bench) ----------------
__global__ void zbl_fallback(const int* __restrict__ neighbors,
                             const float* __restrict__ mask,
                             const float* __restrict__ dist,
                             const unsigned short* __restrict__ packed,
                             const float* __restrict__ scal,
                             float* __restrict__ out,
                             int N, int K, int epb, int total_edges)
{
    const int e = blockIdx.x * blockDim.x + threadIdx.x;
    if (e >= total_edges) return;
    const float w1 = scal[1], w2 = scal[2], w3 = scal[3], w4 = scal[4];
    const float e1 = scal[5], e2 = scal[6], e3 = scal[7], e4 = scal[8];
    const float qb = scal[9], qs = scal[10];
    const int b = e / epb;
    const int n = (e - b * epb) / K;
    const unsigned int wi = packed[(size_t)b * N + n];
    const unsigned int wj = packed[(size_t)b * N + neighbors[e]];
    const float zpi = fmaf((float)(wi >> 7), qs, qb);
    const float zpj = fmaf((float)(wj >> 7), qs, qb);
    const float Zi = (float)(wi & 0x7Fu), Zj = (float)(wj & 0x7Fu);
    const float m = mask[e], d = dist[e];
    const float a  = (zpi + zpj) * m;
    const float ad = a * d;
    const float f = w1 * exp2f(e1 * ad) + w2 * exp2f(e2 * ad)
                  + w3 * exp2f(e3 * ad) + w4 * exp2f(e4 * ad);
    const float corr = (m != 0.f) ? (f * Zi * Zj * m / d) : 0.f;
    if (corr != 0.f) atomicAdd(&out[b], corr);
}

extern "C" void kernel_launch(void* const* d_in, const int* in_sizes, int n_in,
                              void* d_out, int out_size, void* d_ws, size_t ws_size,
                              hipStream_t stream) {
    const int*   neighbors = (const int*)  d_in[0];
    const float* nb_mask   = (const float*)d_in[1];
    const int*   zn        = (const int*)  d_in[2];
    const float* dist      = (const float*)d_in[3];
    const float* adiv = (const float*)d_in[4];
    const float* apow = (const float*)d_in[5];
    const float* c1 = (const float*)d_in[6];
    const float* c2 = (const float*)d_in[7];
    const float* c3 = (const float*)d_in[8];
    const float* c4 = (const float*)d_in[9];
    const float* a1 = (const float*)d_in[10];
    const float* a2 = (const float*)d_in[11];
    const float* a3 = (const float*)d_in[12];
    const float* a4 = (const float*)d_in[13];

    const int total_edges = in_sizes[0];   // B*N*K
    const int total_atoms = in_sizes[2];   // B*N
    const int B = out_size;                // [B,1] fp32 output
    const int N = total_atoms / B;
    const int K = total_edges / total_atoms;
    const int epb = N * K;

    float*          scal   = (float*)d_ws;                         // 11 f32
    unsigned short* packed = (unsigned short*)((char*)d_ws + 64);  // B*N u16

    hipMemsetAsync(d_out, 0, (size_t)out_size * sizeof(float), stream);

    {
        const int threads = 256;
        const int blocks = (total_atoms + threads - 1) / threads;
        zbl_pre<<<blocks, threads, 0, stream>>>(zn, adiv, apow, c1, c2, c3, c4,
                                                a1, a2, a3, a4,
                                                packed, scal, total_atoms);
    }

    int kshift = 0;
    while ((1 << kshift) < K && kshift < 30) kshift++;
    const bool kpow2 = ((1 << kshift) == K);

    // fast path: iters=32 per wave, 8 waves/block, granule 64
    const int ITERS = 32;
    const int span_block = WPB * GRAN * ITERS;          // 16384 edges/block
    const size_t lds_dyn = (size_t)N * 2;
    const bool fast = kpow2 && (N % 8 == 0) && (N <= 8192) &&
                      (epb % span_block == 0) &&
                      ((size_t)(64 + (size_t)total_atoms * 2) <= ws_size);
    if (fast) {
        const int bpb = epb / span_block;               // blocks per batch
        dim3 grid(bpb, B);
        zbl_main7<<<grid, 512, lds_dyn, stream>>>(
            neighbors, nb_mask, dist, packed, scal, (float*)d_out,
            N, kshift, epb, ITERS);
    } else {
        const int threads = 256;
        const int blocks = (total_edges + threads - 1) / threads;
        zbl_fallback<<<blocks, threads, 0, stream>>>(
            neighbors, nb_mask, dist, packed, scal, (float*)d_out,
            N, K, epb, total_edges);
    }
}

// Round 8
// 51.751 us; speedup vs baseline: 1.5502x; 1.0417x over previous
//
#include <hip/hip_runtime.h>

// ZBL repulsion energy: out[b] = sum_{n,k} KEHALF * f(a*d) * Zi*Zj*mask / d
// B=16, N=8192, K=128 in the bench (shapes derived from in_sizes).
//
// Round-8 (on top of R7's depth-4 counted-vmcnt ring @ 32 waves/CU):
//  - ONE global_load_lds per slot (width 16): lanes 0-15 idx, 16-31 mask,
//    32-47 dist (per-lane global addresses; LDS dest = lane*16 keeps the
//    256|256|256 slot layout). 3x fewer vmem instrs; steady vmcnt(3).
//  - VALU diet: f = sum_i exp2(e_i*ad + log2(w_i)) (weights folded into
//    exponent); drop the mask cmp/cndmask (zz=0 already kills masked edges).

#define KEHALF_F 7.199822675975274f
#define LOG2E_F  1.4426950408889634f
#define DEPTH    4
#define GRAN     64       // edges per wave-iteration
#define WPB      8        // waves per block (512 threads)
#define SLOTB    768      // 256B idx + 256B mask + 256B dist

__device__ __forceinline__ float softplus_f(float x) {
    return (x > 20.f) ? x : log1pf(__expf(x));
}

// ---------------- precompute: scalars + packed u16 per-atom table ----------------
// scal: [0]=sad [1..4]=w_i (KEHALF folded) [5..8]=e_i(=-sp(a_i)*log2e)
//       [9]=qb [10]=qs [11..14]=log2(w_i)
__global__ void zbl_pre(const int* __restrict__ zn,
                        const float* __restrict__ adiv,
                        const float* __restrict__ apow,
                        const float* __restrict__ c1, const float* __restrict__ c2,
                        const float* __restrict__ c3, const float* __restrict__ c4,
                        const float* __restrict__ a1, const float* __restrict__ a2,
                        const float* __restrict__ a3, const float* __restrict__ a4,
                        unsigned short* __restrict__ packed, float* __restrict__ scal,
                        int total_atoms)
{
    int i = blockIdx.x * blockDim.x + threadIdx.x;
    const float spa = softplus_f(apow[0]);
    const float sad = softplus_f(adiv[0]);
    const float qb  = sad;                                  // Z=1 -> zps=sad
    const float qmax = sad * __expf(spa * __logf(94.f));
    const float qs  = (qmax - qb) * (1.f / 511.f);
    if (i == 0) {
        float s1 = softplus_f(c1[0]), s2 = softplus_f(c2[0]);
        float s3 = softplus_f(c3[0]), s4 = softplus_f(c4[0]);
        float inv = KEHALF_F / (s1 + s2 + s3 + s4);         // fold KEHALF
        float w1 = s1 * inv, w2 = s2 * inv, w3 = s3 * inv, w4 = s4 * inv;
        scal[0] = sad;
        scal[1] = w1; scal[2] = w2; scal[3] = w3; scal[4] = w4;
        scal[5] = -softplus_f(a1[0]) * LOG2E_F;             // exp2 exponents
        scal[6] = -softplus_f(a2[0]) * LOG2E_F;
        scal[7] = -softplus_f(a3[0]) * LOG2E_F;
        scal[8] = -softplus_f(a4[0]) * LOG2E_F;
        scal[9]  = qb;
        scal[10] = qs;
        scal[11] = __log2f(w1);                             // weight -> exponent
        scal[12] = __log2f(w2);
        scal[13] = __log2f(w3);
        scal[14] = __log2f(w4);
    }
    if (i < total_atoms) {
        unsigned int Z = (unsigned int)zn[i];
        float Zf = (float)Z;
        float zps = sad * __expf(spa * __logf(Zf));         // sp(adiv) * Z^sp(apow)
        float qf = (zps - qb) / qs;
        int q = (int)(qf + 0.5f);
        if (q < 0) q = 0;
        if (q > 511) q = 511;
        packed[i] = (unsigned short)(((unsigned)q << 7) | (Z & 0x7Fu));
    }
}

// ---------------- main: depth-4 async ring (1 vmem instr/slot), 32 waves/CU ----------------
extern __shared__ unsigned short tab[];   // N u16 (dynamic, after static)

// one width-16 global_load_lds stages the whole 768B slot:
// lanes 0-15 -> idx bytes [0,256), 16-31 -> mask [256,512), 32-47 -> dist [512,768)
#define STAGE1(slotp, it) do {                                                    \
    const char* _g = (lane < 16) ? (const char*)(nb_ + ((it) << 6))               \
                   : (lane < 32) ? (const char*)(mk_ + ((it) << 6))               \
                                 : (const char*)(ds_ + ((it) << 6));              \
    _g += (lane & 15) * 16;                                                       \
    if (lane < 48)                                                                \
        __builtin_amdgcn_global_load_lds(                                         \
            (const __attribute__((address_space(1))) void*)_g,                    \
            (__attribute__((address_space(3))) void*)(slotp), 16, 0, 0);          \
} while (0)

#define CONSUME(sp, it) do {                                                      \
    const int   ji = *(const int*)  ((sp) + (lane << 2));                         \
    const float mm = *(const float*)((sp) + 256 + (lane << 2));                   \
    const float dd = *(const float*)((sp) + 512 + (lane << 2));                   \
    const int r = rw + ((it) << 6) + lane;                                        \
    const unsigned int wi_ = tab[r >> kshift];                                    \
    const unsigned int wj_ = tab[ji];                                             \
    const float zpi = fmaf((float)(wi_ >> 7), qs, qb);                            \
    const float Zi  = (float)(wi_ & 0x7Fu);                                       \
    const float zpj = fmaf((float)(wj_ >> 7), qs, qb);                            \
    const float Zj  = (float)(wj_ & 0x7Fu);                                       \
    const float zz = Zi * Zj * mm;                                                \
    const float ad = (zpi + zpj) * (mm * dd);                                     \
    const float f = exp2f(fmaf(e1, ad, l1)) + exp2f(fmaf(e2, ad, l2))             \
                  + exp2f(fmaf(e3, ad, l3)) + exp2f(fmaf(e4, ad, l4));            \
    acc += f * zz * __builtin_amdgcn_rcpf(dd);                                    \
} while (0)

__global__ __launch_bounds__(512, 8) void zbl_main8(
        const int*            __restrict__ neighbors,
        const float*          __restrict__ mask,
        const float*          __restrict__ dist,
        const unsigned short* __restrict__ packed,
        const float*          __restrict__ scal,
        float*                __restrict__ out,
        int N, int kshift, int epb, int iters)
{
    __shared__ char stage[WPB][DEPTH][SLOTB];   // 24576 B static

    const int tid  = threadIdx.x;
    const int w    = tid >> 6;
    const int lane = tid & 63;
    const int b    = blockIdx.y;

    // wave's contiguous edge span within batch b
    const int rw = (blockIdx.x * WPB + w) * (iters * GRAN);
    const size_t ebase = (size_t)b * epb + (size_t)rw;
    const int*   nb_ = neighbors + ebase;
    const float* mk_ = mask      + ebase;
    const float* ds_ = dist      + ebase;

    // 1) tab global loads first (oldest in vmem queue)
    const uint4* s4 = (const uint4*)(packed + (size_t)b * N);
    const int n8 = N >> 3;                      // # of uint4 (<= 1024)
    uint4 tv0, tv1;
    const bool h0 = (tid < n8);
    const bool h1 = (tid + 512 < n8);
    if (h0) tv0 = s4[tid];
    if (h1) tv1 = s4[tid + 512];

    // 2) ring prologue: issue DEPTH slots (1 instr each)
    {
        char* sp0 = &stage[w][0][0]; STAGE1(sp0, 0);
        char* sp1 = &stage[w][1][0]; STAGE1(sp1, 1);
        char* sp2 = &stage[w][2][0]; STAGE1(sp2, 2);
        char* sp3 = &stage[w][3][0]; STAGE1(sp3, 3);
    }

    // 3) write tab to LDS, then barrier
    {
        uint4* t4 = (uint4*)tab;
        if (h0) t4[tid] = tv0;
        if (h1) t4[tid + 512] = tv1;
    }
    const float e1 = scal[5],  e2 = scal[6],  e3 = scal[7],  e4 = scal[8];
    const float qb = scal[9],  qs = scal[10];
    const float l1 = scal[11], l2 = scal[12], l3 = scal[13], l4 = scal[14];
    __syncthreads();

    float acc = 0.f;
    int it = 0;

    // main loop: steady-state counted wait, restage same slot, no barriers
    for (; it < iters - DEPTH; ++it) {
        asm volatile("s_waitcnt vmcnt(3)" ::: "memory");
        char* sp = &stage[w][it & (DEPTH - 1)][0];
        const int   ji = *(const int*)  (sp + (lane << 2));
        const float mm = *(const float*)(sp + 256 + (lane << 2));
        const float dd = *(const float*)(sp + 512 + (lane << 2));
        asm volatile("s_waitcnt lgkmcnt(0)" ::: "memory");   // slot consumed
        STAGE1(sp, it + DEPTH);
        const int r = rw + (it << 6) + lane;
        const unsigned int wi_ = tab[r >> kshift];
        const unsigned int wj_ = tab[ji];
        const float zpi = fmaf((float)(wi_ >> 7), qs, qb);
        const float Zi  = (float)(wi_ & 0x7Fu);
        const float zpj = fmaf((float)(wj_ >> 7), qs, qb);
        const float Zj  = (float)(wj_ & 0x7Fu);
        const float zz = Zi * Zj * mm;
        const float ad = (zpi + zpj) * (mm * dd);
        const float f = exp2f(fmaf(e1, ad, l1)) + exp2f(fmaf(e2, ad, l2))
                      + exp2f(fmaf(e3, ad, l3)) + exp2f(fmaf(e4, ad, l4));
        acc += f * zz * __builtin_amdgcn_rcpf(dd);
    }

    // epilogue: 4 iterations with tightening waits (3/2/1/0), no restage
    {
        asm volatile("s_waitcnt vmcnt(3)" ::: "memory");
        char* sp = &stage[w][it & (DEPTH - 1)][0];
        CONSUME(sp, it); ++it;
    }
    {
        asm volatile("s_waitcnt vmcnt(2)" ::: "memory");
        char* sp = &stage[w][it & (DEPTH - 1)][0];
        CONSUME(sp, it); ++it;
    }
    {
        asm volatile("s_waitcnt vmcnt(1)" ::: "memory");
        char* sp = &stage[w][it & (DEPTH - 1)][0];
        CONSUME(sp, it); ++it;
    }
    {
        asm volatile("s_waitcnt vmcnt(0)" ::: "memory");
        char* sp = &stage[w][it & (DEPTH - 1)][0];
        CONSUME(sp, it); ++it;
    }

    // reduce: wave shuffle, then cross-wave via reused stage LDS, one atomic
    #pragma unroll
    for (int off = 32; off > 0; off >>= 1) acc += __shfl_down(acc, off);
    __syncthreads();                        // all waves past vmcnt(0)
    float* wred = (float*)&stage[0][0][0];  // reuse (all ring traffic done)
    if (lane == 0) wred[w] = acc;
    __syncthreads();
    if (tid == 0) {
        float t = 0.f;
        #pragma unroll
        for (int i = 0; i < WPB; ++i) t += wred[i];
        atomicAdd(&out[b], t);
    }
}

// ---------------- fallback (generic shapes, not used in bench) ----------------
__global__ void zbl_fallback(const int* __restrict__ neighbors,
                             const float* __restrict__ mask,
                             const float* __restrict__ dist,
                             const unsigned short* __restrict__ packed,
                             const float* __restrict__ scal,
                             float* __restrict__ out,
                             int N, int K, int epb, int total_edges)
{
    const int e = blockIdx.x * blockDim.x + threadIdx.x;
    if (e >= total_edges) return;
    const float w1 = scal[1], w2 = scal[2], w3 = scal[3], w4 = scal[4];
    const float e1 = scal[5], e2 = scal[6], e3 = scal[7], e4 = scal[8];
    const float qb = scal[9], qs = scal[10];
    const int b = e / epb;
    const int n = (e - b * epb) / K;
    const unsigned int wi = packed[(size_t)b * N + n];
    const unsigned int wj = packed[(size_t)b * N + neighbors[e]];
    const float zpi = fmaf((float)(wi >> 7), qs, qb);
    const float zpj = fmaf((float)(wj >> 7), qs, qb);
    const float Zi = (float)(wi & 0x7Fu), Zj = (float)(wj & 0x7Fu);
    const float m = mask[e], d = dist[e];
    const float a  = (zpi + zpj) * m;
    const float ad = a * d;
    const float f = w1 * exp2f(e1 * ad) + w2 * exp2f(e2 * ad)
                  + w3 * exp2f(e3 * ad) + w4 * exp2f(e4 * ad);
    const float corr = (m != 0.f) ? (f * Zi * Zj * m / d) : 0.f;
    if (corr != 0.f) atomicAdd(&out[b], corr);
}

extern "C" void kernel_launch(void* const* d_in, const int* in_sizes, int n_in,
                              void* d_out, int out_size, void* d_ws, size_t ws_size,
                              hipStream_t stream) {
    const int*   neighbors = (const int*)  d_in[0];
    const float* nb_mask   = (const float*)d_in[1];
    const int*   zn        = (const int*)  d_in[2];
    const float* dist      = (const float*)d_in[3];
    const float* adiv = (const float*)d_in[4];
    const float* apow = (const float*)d_in[5];
    const float* c1 = (const float*)d_in[6];
    const float* c2 = (const float*)d_in[7];
    const float* c3 = (const float*)d_in[8];
    const float* c4 = (const float*)d_in[9];
    const float* a1 = (const float*)d_in[10];
    const float* a2 = (const float*)d_in[11];
    const float* a3 = (const float*)d_in[12];
    const float* a4 = (const float*)d_in[13];

    const int total_edges = in_sizes[0];   // B*N*K
    const int total_atoms = in_sizes[2];   // B*N
    const int B = out_size;                // [B,1] fp32 output
    const int N = total_atoms / B;
    const int K = total_edges / total_atoms;
    const int epb = N * K;

    float*          scal   = (float*)d_ws;                         // 15 f32
    unsigned short* packed = (unsigned short*)((char*)d_ws + 64);  // B*N u16

    hipMemsetAsync(d_out, 0, (size_t)out_size * sizeof(float), stream);

    {
        const int threads = 256;
        const int blocks = (total_atoms + threads - 1) / threads;
        zbl_pre<<<blocks, threads, 0, stream>>>(zn, adiv, apow, c1, c2, c3, c4,
                                                a1, a2, a3, a4,
                                                packed, scal, total_atoms);
    }

    int kshift = 0;
    while ((1 << kshift) < K && kshift < 30) kshift++;
    const bool kpow2 = ((1 << kshift) == K);

    // fast path: iters=32 per wave, 8 waves/block, granule 64
    const int ITERS = 32;
    const int span_block = WPB * GRAN * ITERS;          // 16384 edges/block
    const size_t lds_dyn = (size_t)N * 2;
    const bool fast = kpow2 && (N % 8 == 0) && (N <= 8192) &&
                      (epb % span_block == 0) &&
                      ((size_t)(64 + (size_t)total_atoms * 2) <= ws_size);
    if (fast) {
        const int bpb = epb / span_block;               // blocks per batch
        dim3 grid(bpb, B);
        zbl_main8<<<grid, 512, lds_dyn, stream>>>(
            neighbors, nb_mask, dist, packed, scal, (float*)d_out,
            N, kshift, epb, ITERS);
    } else {
        const int threads = 256;
        const int blocks = (total_edges + threads - 1) / threads;
        zbl_fallback<<<blocks, threads, 0, stream>>>(
            neighbors, nb_mask, dist, packed, scal, (float*)d_out,
            N, K, epb, total_edges);
    }
}